// Round 8
// baseline (385.007 us; speedup 1.0000x reference)
//
#include <hip/hip_runtime.h>
#include <math.h>

#define ROWS 64
#define TLEN 64000
#define NFR 251
#define NMELS 80
#define NFB 131072            // big FFT length (>= 2*T-1 -> exact linear conv)
#define PI2F 6.28318530717958647692f
#define PI_F 3.14159265358979323846f

// banked double accumulators:
// 0 S_dt  1 S_rt  2 S_sp  3..6 E0..E3  7 S_mag  8 S_cos  9 S_mel  10 S_c
__device__ double g_part[64][12];

// slot holding k2 after per-lane radix-4 FFT16 (digit reversal, involution)
__device__ constexpr int DR[16] = {0,4,8,12,1,5,9,13,2,6,10,14,3,7,11,15};
// mirror slot: RM[r] = DR[16 - DR[r]]
__device__ constexpr int RM[16] = {0,3,2,1,15,14,13,12,11,10,9,8,7,6,5,4};

__device__ inline int dr4(int i){ return ((i & 3) << 2) | (i >> 2); }  // DR, runtime
// bank-conflict-free swizzle for stride-16 writes into 513-entry arrays
__device__ inline int SW(int k){ return k + (k >> 5); }

__device__ inline void atomAddD(double* p, double v){
  __hip_atomic_fetch_add(p, v, __ATOMIC_RELAXED, __HIP_MEMORY_SCOPE_AGENT);
}
__device__ inline int brev6(int x){ return (int)((unsigned)__brev((unsigned)x) >> 26); }
__device__ inline float2 cmul(float2 a, float2 b){
  return make_float2(a.x*b.x - a.y*b.y, a.x*b.y + a.y*b.x);
}
__device__ inline float wred(float v){
#pragma unroll
  for (int o = 32; o > 0; o >>= 1) v += __shfl_down(v, o, 64);
  return v;
}

// ---------- per-wave FFT cores (forward DIF: natural in, bit-reversed out) ----------
template<int S, int N>
__device__ inline void fft64_lanes(float2* v, int l){
  float2 W[5];
#pragma unroll
  for (int si = 0; si < 5; ++si){
    int d = 32 >> si;
    float a = (float)S * PI_F * (float)(l & (d-1)) * (1.0f/(float)d);
    float sn, cs; __sincosf(a, &sn, &cs);
    W[si] = make_float2(cs, sn);
  }
#pragma unroll
  for (int rr = 0; rr < N; ++rr){
    float2 x = v[rr];
#pragma unroll
    for (int si = 0; si < 6; ++si){
      int d = 32 >> si;
      float tx = __shfl_xor(x.x, d, 64);
      float ty = __shfl_xor(x.y, d, 64);
      bool hi = (l & d) != 0;
      float sx = x.x + tx, sy = x.y + ty;
      float dx = tx - x.x, dy = ty - x.y;
      float rx, ry;
      if (si < 5){ rx = dx*W[si].x - dy*W[si].y; ry = dx*W[si].y + dy*W[si].x; }
      else       { rx = dx; ry = dy; }
      x.x = hi ? rx : sx;
      x.y = hi ? ry : sy;
    }
    v[rr] = x;
  }
}

template<int S>
__device__ inline void fft16_reg(float2* v){
  const float Sf = (float)S;
  const float C1 = 0.9238795325112867f, S1 = 0.3826834323650898f, C2 = 0.7071067811865476f;
  const float2 W1[4] = {{1.f,0.f},{C1,Sf*S1},{C2,Sf*C2},{S1,Sf*C1}};
  const float2 W2[4] = {{1.f,0.f},{C2,Sf*C2},{0.f,Sf},{-C2,Sf*C2}};
  const float2 W3[4] = {{1.f,0.f},{S1,Sf*C1},{-C2,Sf*C2},{-C1,-Sf*S1}};
#pragma unroll
  for (int j = 0; j < 4; ++j){
    float2 x0=v[j], x1=v[j+4], x2=v[j+8], x3=v[j+12];
    float2 t0={x0.x+x2.x, x0.y+x2.y}, t1={x0.x-x2.x, x0.y-x2.y};
    float2 t2={x1.x+x3.x, x1.y+x3.y}, t3={x1.x-x3.x, x1.y-x3.y};
    float2 y0={t0.x+t2.x, t0.y+t2.y};
    float2 y2={t0.x-t2.x, t0.y-t2.y};
    float2 y1={t1.x - Sf*t3.y, t1.y + Sf*t3.x};
    float2 y3={t1.x + Sf*t3.y, t1.y - Sf*t3.x};
    v[j]=y0; v[j+4]=cmul(y1,W1[j]); v[j+8]=cmul(y2,W2[j]); v[j+12]=cmul(y3,W3[j]);
  }
#pragma unroll
  for (int b = 0; b < 4; ++b){
    float2 x0=v[4*b], x1=v[4*b+1], x2=v[4*b+2], x3=v[4*b+3];
    float2 t0={x0.x+x2.x, x0.y+x2.y}, t1={x0.x-x2.x, x0.y-x2.y};
    float2 t2={x1.x+x3.x, x1.y+x3.y}, t3={x1.x-x3.x, x1.y-x3.y};
    v[4*b]   = make_float2(t0.x+t2.x, t0.y+t2.y);
    v[4*b+2] = make_float2(t0.x-t2.x, t0.y-t2.y);
    v[4*b+1] = make_float2(t1.x - Sf*t3.y, t1.y + Sf*t3.x);
    v[4*b+3] = make_float2(t1.x + Sf*t3.y, t1.y - Sf*t3.x);
  }
}

// 1024-pt forward: input v[m]=x[l+64m]; output slot rr, lane l = X[DR[rr]+16*brev6(l)]
template<int S>
__device__ inline void fft1024_wave(float2* v, int l){
  fft16_reg<S>(v);
  float a = (float)S * PI2F * (float)l * (1.0f/1024.0f);
  float sn, cs; __sincosf(a, &sn, &cs);
  float2 T = make_float2(cs, sn);
  float2 cur = T;
#pragma unroll
  for (int k2 = 1; k2 < 16; ++k2){
    v[DR[k2]] = cmul(v[DR[k2]], cur);
    if (k2 < 15) cur = cmul(cur, T);
  }
  fft64_lanes<S,16>(v, l);
}

// 128-pt forward: input v[m]=x[l+64m]; output slot rr, lane l = X[rr+2*brev6(l)]
template<int S>
__device__ inline void fft128_wave(float2* v, int l){
  float2 a = {v[0].x+v[1].x, v[0].y+v[1].y};
  float2 b = {v[0].x-v[1].x, v[0].y-v[1].y};
  float ang = (float)S * PI_F * (float)l * (1.0f/64.0f);
  float sn, cs; __sincosf(ang, &sn, &cs);
  v[0] = a; v[1] = cmul(b, make_float2(cs, sn));
  fft64_lanes<S,2>(v, l);
}

// ---------- adjoint (DIT) inverses: bit-reversed in, natural out, unnormalized ----------
template<int N>
__device__ inline void ifft64_lanes(float2* v, int l){
  float2 W[5];
#pragma unroll
  for (int si = 0; si < 5; ++si){
    int d = 32 >> si;
    float a = PI_F * (float)(l & (d-1)) * (1.0f/(float)d);   // conj of forward
    float sn, cs; __sincosf(a, &sn, &cs);
    W[si] = make_float2(cs, sn);
  }
#pragma unroll
  for (int rr = 0; rr < N; ++rr){
    float2 x = v[rr];
#pragma unroll
    for (int si = 5; si >= 0; --si){
      int d = 32 >> si;
      bool hi = (l & d) != 0;
      float2 xp = x;
      if (si < 5 && hi) xp = cmul(x, W[si]);
      float tx = __shfl_xor(xp.x, d, 64);
      float ty = __shfl_xor(xp.y, d, 64);
      x.x = hi ? (tx - xp.x) : (xp.x + tx);
      x.y = hi ? (ty - xp.y) : (xp.y + ty);
    }
    v[rr] = x;
  }
}

__device__ inline void r4p(float2* v, int i0, int i1, int i2, int i3){
  float2 x0=v[i0], x1=v[i1], x2=v[i2], x3=v[i3];
  float2 t0={x0.x+x2.x, x0.y+x2.y}, t1={x0.x-x2.x, x0.y-x2.y};
  float2 t2={x1.x+x3.x, x1.y+x3.y}, t3={x1.x-x3.x, x1.y-x3.y};
  v[i0] = make_float2(t0.x+t2.x, t0.y+t2.y);
  v[i2] = make_float2(t0.x-t2.x, t0.y-t2.y);
  v[i1] = make_float2(t1.x - t3.y, t1.y + t3.x);
  v[i3] = make_float2(t1.x + t3.y, t1.y - t3.x);
}

__device__ inline void ifft16_reg(float2* v){
#pragma unroll
  for (int b = 0; b < 4; ++b) r4p(v, 4*b, 4*b+1, 4*b+2, 4*b+3);
  const float C1 = 0.9238795325112867f, S1 = 0.3826834323650898f, C2 = 0.7071067811865476f;
  const float2 W1[4] = {{1.f,0.f},{C1,S1},{C2,C2},{S1,C1}};
  const float2 W2[4] = {{1.f,0.f},{C2,C2},{0.f,1.f},{-C2,C2}};
  const float2 W3[4] = {{1.f,0.f},{S1,C1},{-C2,C2},{-C1,-S1}};
#pragma unroll
  for (int j = 1; j < 4; ++j){
    v[j+4]  = cmul(v[j+4],  W1[j]);
    v[j+8]  = cmul(v[j+8],  W2[j]);
    v[j+12] = cmul(v[j+12], W3[j]);
  }
#pragma unroll
  for (int j = 0; j < 4; ++j) r4p(v, j, j+4, j+8, j+12);
}

// input slot rr, lane l = X[rr+2*brev6(l)]; output v[m], lane l = 128*x[l+64m]
__device__ inline void ifft128_wave(float2* v, int l){
  ifft64_lanes<2>(v, l);
  float ang = PI_F * (float)l * (1.0f/64.0f);
  float sn, cs; __sincosf(ang, &sn, &cs);
  v[1] = cmul(v[1], make_float2(cs, sn));
  float2 a = {v[0].x+v[1].x, v[0].y+v[1].y};
  float2 b = {v[0].x-v[1].x, v[0].y-v[1].y};
  v[0] = a; v[1] = b;
}

// input slot rr, lane l = X[DR[rr]+16*brev6(l)]; output v[m], lane l = 1024*x[l+64m]
__device__ inline void ifft1024_wave(float2* v, int l){
  ifft64_lanes<16>(v, l);
  float a = PI2F * (float)l * (1.0f/1024.0f);
  float sn, cs; __sincosf(a, &sn, &cs);
  float2 T = make_float2(cs, sn);
  float2 cur = T;
#pragma unroll
  for (int k2 = 1; k2 < 16; ++k2){
    v[DR[k2]] = cmul(v[DR[k2]], cur);
    if (k2 < 15) cur = cmul(cur, T);
  }
  ifft16_reg(v);
}

// ---------------- init: zero accumulators ----------------
extern "C" __global__ void __launch_bounds__(256) k_init(){
  int t = blockIdx.x*256 + threadIdx.x;
  if (t < 768) ((double*)g_part)[t] = 0.0;
}

// ---------------- time-domain losses + rir segment energies (float4) -------
extern "C" __global__ void __launch_bounds__(256) k_time(
    const float* __restrict__ pd, const float* __restrict__ td,
    const float* __restrict__ pr, const float* __restrict__ tr){
  const int N4 = ROWS*TLEN/4;          // 1,024,000 float4s; 16000 per row
  int stride = gridDim.x * 256;
  float sdt=0.f, srt=0.f, ssp=0.f, e0=0.f, e1=0.f, e2=0.f, e3=0.f;
  const float4* pd4 = (const float4*)pd;
  const float4* td4 = (const float4*)td;
  const float4* pr4 = (const float4*)pr;
  const float4* tr4 = (const float4*)tr;
  for (int i = blockIdx.x*256 + threadIdx.x; i < N4; i += stride){
    float4 a = pd4[i], b = td4[i], p = pr4[i], q = tr4[i];
    sdt += fabsf(a.x-b.x)+fabsf(a.y-b.y)+fabsf(a.z-b.z)+fabsf(a.w-b.w);
    srt += fabsf(p.x-q.x)+fabsf(p.y-q.y)+fabsf(p.z-q.z)+fabsf(p.w-q.w);
    ssp += fabsf(p.x)+fabsf(p.y)+fabsf(p.z)+fabsf(p.w);
    float p2 = p.x*p.x + p.y*p.y + p.z*p.z + p.w*p.w;
    int seg = (i % 16000) / 4000;      // uniform for all 4 elems
    if (seg == 0) e0 += p2; else if (seg == 1) e1 += p2;
    else if (seg == 2) e2 += p2; else e3 += p2;
  }
  sdt = wred(sdt); srt = wred(srt); ssp = wred(ssp);
  e0 = wred(e0); e1 = wred(e1); e2 = wred(e2); e3 = wred(e3);
  if ((threadIdx.x & 63) == 0){
    int bank = (blockIdx.x*4 + (threadIdx.x >> 6)) & 63;
    atomAddD(&g_part[bank][0], (double)sdt);
    atomAddD(&g_part[bank][1], (double)srt);
    atomAddD(&g_part[bank][2], (double)ssp);
    atomAddD(&g_part[bank][3], (double)e0);
    atomAddD(&g_part[bank][4], (double)e1);
    atomAddD(&g_part[bank][5], (double)e2);
    atomAddD(&g_part[bank][6], (double)e3);
  }
}

// ---------------- fused STFT (freq + mel) losses, one wave per frame --------
extern "C" __global__ void __launch_bounds__(256) k_stft(
    const float* __restrict__ pd, const float* __restrict__ td){
  __shared__ float2 spec0[4][64];
  __shared__ float pp[4][532], tt[4][532];   // swizzled index SW(k)=k+(k>>5)
  __shared__ float win[1024];
  __shared__ float fpts[82], cw[532];
  __shared__ int   bstart[82];
  int wid = threadIdx.x >> 6, l = threadIdx.x & 63;
  int tid = threadIdx.x;
  const float scale = 0.05103103630798288f;   // 1/sqrt(384), folded into window
  for (int j = tid; j < 1024; j += 256)
    win[j] = (0.5f - 0.5f*__cosf((PI2F/1024.0f)*(float)j)) * scale;
  if (tid < 82){
    const float maxmel = 2595.0f * log10f(1.0f + 8000.0f/700.0f);
    fpts[tid] = 700.0f*(exp10f(maxmel*(float)tid*(1.0f/81.0f)*(1.0f/2595.0f)) - 1.0f);
  }
  __syncthreads();
  // per-bin up-weight c[k] (down-weight = 1-c), filter boundaries bstart
  for (int k = tid; k < 513; k += 256){
    float fk = 15.625f * (float)k;
    int j = 0;
#pragma unroll
    for (int step = 64; step; step >>= 1){
      int cand = j + step;
      if (cand <= 81 && fpts[cand] <= fk) j = cand;
    }
    if (j > 80) j = 80;
    cw[SW(k)] = (fk - fpts[j]) / (fpts[j+1] - fpts[j]);
  }
  if (tid < 82){
    int b = (int)ceilf(fpts[tid] * (1.0f/15.625f));
    if (b < 0) b = 0; if (b > 513) b = 513;
    bstart[tid] = b;
  }
  __syncthreads();                      // cw/bstart visible to all waves
  int frame = blockIdx.x*4 + wid;
  int r = frame / NFR, fr = frame - r*NFR;
  const float* pdr = pd + (size_t)r*TLEN;
  const float* tdr = td + (size_t)r*TLEN;
  int base = fr*256 - 512;
  float2 v[16];
#pragma unroll
  for (int m = 0; m < 16; ++m){
    int j = l + 64*m;
    int g = base + j;
    g = (g < 0) ? -g : ((g >= TLEN) ? (2*TLEN - 2 - g) : g);
    float w = win[j];
    v[m] = make_float2(pdr[g]*w, tdr[g]*w);
  }
  fft1024_wave<-1>(v, l);
  int kb = brev6(l);
  spec0[wid][kb] = v[0];          // the k2=0 line: Z[16*k1] at index k1
  float magp = 0.f, cosp = 0.f;
  // k2 = 1..15 lines: mirror of (slot rr, lane l) is (slot RM[rr], lane l^63).
  // Each unordered (k,1024-k) pair enumerated twice -> weight 0.5 (dup writes identical).
#pragma unroll
  for (int rr = 1; rr < 16; ++rr){
    float2 z = v[rr];
    float2 zm;
    zm.x = __shfl_xor(v[RM[rr]].x, 63, 64);
    zm.y = __shfl_xor(v[RM[rr]].y, 63, 64);
    int k = DR[rr] + 16*kb;
    float px = 0.5f*(z.x + zm.x), py = 0.5f*(z.y - zm.y);
    float tx = 0.5f*(z.y + zm.y), ty = -0.5f*(z.x - zm.x);
    float ppk = px*px + py*py, ttk = tx*tx + ty*ty;
    float rp = rsqrtf(fmaxf(ppk, 1e-30f)), rt = rsqrtf(fmaxf(ttk, 1e-30f));
    magp += 0.5f*fabsf(ppk*rp - ttk*rt);
    cosp += 0.5f*((px*tx + py*ty)*rp*rt);
    int kk = (k <= 512) ? k : 1024 - k;
    pp[wid][SW(kk)] = ppk; tt[wid][SW(kk)] = ttk;
  }
  if (l <= 32){                    // k = 16*l, weight 1
    float2 z  = spec0[wid][l];
    float2 zm = spec0[wid][(64 - l) & 63];
    float px = 0.5f*(z.x + zm.x), py = 0.5f*(z.y - zm.y);
    float tx = 0.5f*(z.y + zm.y), ty = -0.5f*(z.x - zm.x);
    float ppk = px*px + py*py, ttk = tx*tx + ty*ty;
    float rp = rsqrtf(fmaxf(ppk, 1e-30f)), rt = rsqrtf(fmaxf(ttk, 1e-30f));
    magp += fabsf(ppk*rp - ttk*rt);
    cosp += (px*tx + py*ty)*rp*rt;
    pp[wid][SW(16*l)] = ppk; tt[wid][SW(16*l)] = ttk;
  }
  // mel: same-wave pp/tt (program order); cw/bstart synced above
  float melp = 0.f;
#pragma unroll
  for (int pass = 0; pass < 2; ++pass){
    int m = l + 64*pass;
    if (m < NMELS){
      int s0 = bstart[m], s1 = bstart[m+1], s2 = bstart[m+2];
      float pm = 0.f, tm = 0.f;
      for (int k = s0; k < s1; ++k){
        int sk = SW(k); float cc = cw[sk];
        pm += cc*pp[wid][sk]; tm += cc*tt[wid][sk];
      }
      for (int k = s1; k < s2; ++k){
        int sk = SW(k); float cc = 1.0f - cw[sk];
        pm += cc*pp[wid][sk]; tm += cc*tt[wid][sk];
      }
      melp += fabsf(__logf(pm + 1e-8f) - __logf(tm + 1e-8f));
    }
  }
  magp = wred(magp); cosp = wred(cosp); melp = wred(melp);
  if (l == 0){
    int bank = (blockIdx.x*4 + wid) & 63;
    atomAddD(&g_part[bank][7], (double)magp);
    atomAddD(&g_part[bank][8], (double)cosp);
    atomAddD(&g_part[bank][9], (double)melp);
  }
}

// ---------------- consistency: four-step FFT of 131072 = 128 x 1024 ---------
// n = n1 + 128*n2 ; storage: buf[s*128 + n1], s = rr*64 + l
// fwd1: block = 4 waves = 4 adjacent n1 (grid 32 x nr for CU utilization).
extern "C" __global__ void __launch_bounds__(256) k_fwd1(
    const float* __restrict__ pd, const float* __restrict__ pr,
    float2* __restrict__ buf, int row0){
  __shared__ float SM[5008];                     // 20 KB, phase-aliased
  float* LA = SM;                                // [500][5] floats (a)
  float* LB = SM + 2500;                         // [500][5] floats (b)
  float2* LT = (float2*)SM;                      // [4][513] float2 (chunks)
  int wid = threadIdx.x >> 6, l = threadIdx.x & 63;
  int tid = threadIdx.x;
  int rl = blockIdx.y;
  int n1base = blockIdx.x * 4;
  int n1 = n1base + wid;
  const float* a = pd + (size_t)(row0+rl)*TLEN;
  const float* b = pr + (size_t)(row0+rl)*TLEN;
  for (int n2 = tid; n2 < 500; n2 += 256){
    float4 va = *(const float4*)&a[n1base + 128*n2];
    float4 vb = *(const float4*)&b[n1base + 128*n2];
    LA[n2*5+0]=va.x; LA[n2*5+1]=va.y; LA[n2*5+2]=va.z; LA[n2*5+3]=va.w;
    LB[n2*5+0]=vb.x; LB[n2*5+1]=vb.y; LB[n2*5+2]=vb.z; LB[n2*5+3]=vb.w;
  }
  __syncthreads();
  float2 v[16];
#pragma unroll
  for (int m = 0; m < 16; ++m){
    int n2 = l + 64*m;
    if (n2 < 500) v[m] = make_float2(LA[n2*5 + wid], LB[n2*5 + wid]);
    else          v[m] = make_float2(0.f, 0.f);
  }
  __syncthreads();                                // LA/LB reads done (LT aliases)
  fft1024_wave<-1>(v, l);
  int kb = brev6(l);
  const float tw = -(PI2F / (float)NFB);
#pragma unroll
  for (int rr = 0; rr < 16; ++rr){
    int K = DR[rr] + 16*kb;
    float ang = tw * (float)(n1*K);               // n1*K < 2^24: exact
    float sn, cs; __sincosf(ang, &sn, &cs);
    v[rr] = cmul(v[rr], make_float2(cs, sn));
  }
  float2* rowp = buf + (size_t)rl*NFB;
#pragma unroll
  for (int c = 0; c < 2; ++c){
#pragma unroll
    for (int rrl = 0; rrl < 8; ++rrl)
      LT[wid*513 + rrl*64 + l] = v[c*8 + rrl];
    __syncthreads();
#pragma unroll
    for (int it = 0; it < 4; ++it){
      int pi = tid + it*256;                      // 0..1023
      int s = pi >> 1, h = (pi & 1)*2;            // h in {0,2}
      float2 x = LT[h*513 + s], y = LT[(h+1)*513 + s];
      *(float4*)&rowp[(size_t)(c*512 + s)*128 + n1base + h] =
          make_float4(x.x, x.y, y.x, y.y);
    }
    __syncthreads();
  }
}

// D/R split + product for one element (z) given its mirror partner (zm)
__device__ inline float2 pointmul(float2 z, float2 zm){
  float Dx = 0.5f*(z.x + zm.x), Dy = 0.5f*(z.y - zm.y);
  float Rx = 0.5f*(z.y + zm.y), Ry = -0.5f*(z.x - zm.x);
  return make_float2(Dx*Rx - Dy*Ry, Dx*Ry + Dy*Rx);
}

// k_mid: fused fwd2 + pointwise + inv1. One wave per conjugate row pair.
extern "C" __global__ void __launch_bounds__(256) k_mid(float2* __restrict__ buf){
  int wid = threadIdx.x >> 6, l = threadIdx.x & 63;
  int p = blockIdx.x*4 + wid;           // pair id = k2 of row A, 0..512
  if (p > 512) return;
  int k2A = p, k2B = (1024 - p) & 1023;
  int sA = dr4(k2A & 15)*64 + brev6(k2A >> 4);
  int sB = dr4(k2B & 15)*64 + brev6(k2B >> 4);
  float2* base = buf + (size_t)blockIdx.y*NFB;
  float2* rA = base + (size_t)sA*128;
  float2* rB = base + (size_t)sB*128;
  bool pair = (sB != sA);
  float2 vA[2] = { rA[l], rA[l+64] };
  float2 vB[2];
  if (pair){ vB[0] = rB[l]; vB[1] = rB[l+64]; }
  fft128_wave<-1>(vA, l);
  if (pair) fft128_wave<-1>(vB, l);
  float2 cA[2];
  if (p == 0){
    int kb = brev6(l);
    int q0 = brev6((64 - kb) & 63);
    float2 zm0 = { __shfl(vA[0].x, q0, 64), __shfl(vA[0].y, q0, 64) };
    float2 zm1 = { __shfl_xor(vA[1].x, 63, 64), __shfl_xor(vA[1].y, 63, 64) };
    cA[0] = pointmul(vA[0], zm0);
    cA[1] = pointmul(vA[1], zm1);
  } else {
    const float2* src = pair ? vB : vA;   // p==512 self-pairs within its own row
    float2 zm0 = { __shfl_xor(src[1].x, 63, 64), __shfl_xor(src[1].y, 63, 64) };
    float2 zm1 = { __shfl_xor(src[0].x, 63, 64), __shfl_xor(src[0].y, 63, 64) };
    cA[0] = pointmul(vA[0], zm0);
    cA[1] = pointmul(vA[1], zm1);
  }
  float2 cB[2];
  if (pair){
    cB[0] = make_float2( __shfl_xor(cA[1].x, 63, 64), -__shfl_xor(cA[1].y, 63, 64) );
    cB[1] = make_float2( __shfl_xor(cA[0].x, 63, 64), -__shfl_xor(cA[0].y, 63, 64) );
  }
  const float twi = PI2F / (float)NFB;
  ifft128_wave(cA, l);
#pragma unroll
  for (int rr = 0; rr < 2; ++rr){
    int n1 = l + 64*rr;
    float ang = twi * (float)(n1*k2A);
    float sn, cs; __sincosf(ang, &sn, &cs);
    rA[n1] = cmul(cA[rr], make_float2(cs, sn));
  }
  if (pair){
    ifft128_wave(cB, l);
#pragma unroll
    for (int rr = 0; rr < 2; ++rr){
      int n1 = l + 64*rr;
      float ang = twi * (float)(n1*k2B);
      float sn, cs; __sincosf(ang, &sn, &cs);
      rB[n1] = cmul(cB[rr], make_float2(cs, sn));
    }
  }
}

// inv2: per n1, adjoint inverse 1024-pt FFT (storage order in, natural out);
// 4 waves / 4 n1 per block, chunked LDS-staged coalesced loads + fused L1.
extern "C" __global__ void __launch_bounds__(256) k_inv2(
    const float* __restrict__ mix, float2* __restrict__ buf, int row0){
  __shared__ float SM[5008];                     // 20 KB, phase-aliased
  float2* LT = (float2*)SM;                      // [4][513] float2 (chunks)
  float* LM = SM;                                // [500][5] floats (mix)
  int wid = threadIdx.x >> 6, l = threadIdx.x & 63;
  int tid = threadIdx.x;
  int rl = blockIdx.y;
  int n1base = blockIdx.x * 4;
  float2* rowp = buf + (size_t)rl*NFB;
  float2 v[16];
#pragma unroll
  for (int c = 0; c < 2; ++c){
#pragma unroll
    for (int it = 0; it < 4; ++it){
      int pi = tid + it*256;
      int s = pi >> 1, h = (pi & 1)*2;
      float4 q = *(const float4*)&rowp[(size_t)(c*512 + s)*128 + n1base + h];
      LT[h*513 + s]     = make_float2(q.x, q.y);
      LT[(h+1)*513 + s] = make_float2(q.z, q.w);
    }
    __syncthreads();
#pragma unroll
    for (int rrl = 0; rrl < 8; ++rrl)
      v[c*8 + rrl] = LT[wid*513 + rrl*64 + l];
    __syncthreads();                              // LT reads done before reuse
  }
  const float* mr = mix + (size_t)(row0+rl)*TLEN;
  for (int n2 = tid; n2 < 500; n2 += 256){
    float4 vm = *(const float4*)&mr[n1base + 128*n2];
    LM[n2*5+0]=vm.x; LM[n2*5+1]=vm.y; LM[n2*5+2]=vm.z; LM[n2*5+3]=vm.w;
  }
  ifft1024_wave(v, l);
  __syncthreads();                                // LM ready
  const float invn = 1.0f/(float)NFB;
  float acc = 0.f;
#pragma unroll
  for (int m = 0; m < 16; ++m){
    int n2 = l + 64*m;
    if (n2 < 500)
      acc += fabsf(v[m].x*invn - LM[n2*5 + wid]);
  }
  acc = wred(acc);
  if (l == 0){
    int bank = (blockIdx.x*4 + wid + blockIdx.y*16) & 63;
    atomAddD(&g_part[bank][10], (double)acc);
  }
}

// ---------------- combine ----------------
extern "C" __global__ void __launch_bounds__(64) k_finalize(float* __restrict__ out){
  __shared__ double s[12];
  int t = threadIdx.x;
  if (t < 12){
    double v = 0.0;
    for (int b = 0; b < 64; ++b) v += g_part[b][t];
    s[t] = v;
  }
  __syncthreads();
  if (t == 0){
    double dt = s[0] / 4096000.0;
    double rt = s[1] / 4096000.0;
    double sp = s[2] / 4096000.0;
    double e0 = s[3] / 1024000.0, e1 = s[4] / 1024000.0;
    double e2 = s[5] / 1024000.0, e3 = s[6] / 1024000.0;
    double dec = fmax(e1 - 0.8*e0, 0.0) + fmax(e2 - 0.8*e1, 0.0) + fmax(e3 - 0.8*e2, 0.0);
    double c1 = 8240832.0;              // 64*513*251
    double freq = s[7]/c1 + 0.1*(1.0 - s[8]/c1);
    double mel  = s[9] / 1285120.0;     // 64*80*251
    double cons = s[10] / 4096000.0;
    double total = 3.0*(dt + 0.5*freq + 0.3*mel)
                 + (rt + 0.1*(sp + dec))
                 + 0.2*cons;
    out[0] = (float)total;
  }
}

extern "C" void kernel_launch(void* const* d_in, const int* in_sizes, int n_in,
                              void* d_out, int out_size, void* d_ws, size_t ws_size,
                              hipStream_t stream){
  const float* pd = (const float*)d_in[0];
  const float* pr = (const float*)d_in[1];
  const float* td = (const float*)d_in[2];
  const float* tr = (const float*)d_in[3];
  const float* mx = (const float*)d_in[4];
  float* out = (float*)d_out;
  float2* buf = (float2*)d_ws;

  size_t rowBytes = (size_t)NFB * sizeof(float2);     // 1 MiB per row
  int maxrows = (int)(ws_size / rowBytes);
  if (maxrows > ROWS) maxrows = ROWS;
  if (maxrows < 1) maxrows = 1;

  hipLaunchKernelGGL(k_init, dim3(3), dim3(256), 0, stream);
  hipLaunchKernelGGL(k_time, dim3(2048), dim3(256), 0, stream, pd, td, pr, tr);
  hipLaunchKernelGGL(k_stft, dim3(ROWS*NFR/4), dim3(256), 0, stream, pd, td);
  for (int row0 = 0; row0 < ROWS; row0 += maxrows){
    int nr = ROWS - row0; if (nr > maxrows) nr = maxrows;
    hipLaunchKernelGGL(k_fwd1, dim3(32, nr),  dim3(256), 0, stream, pd, pr, buf, row0);
    hipLaunchKernelGGL(k_mid,  dim3(129, nr), dim3(256), 0, stream, buf);
    hipLaunchKernelGGL(k_inv2, dim3(32, nr),  dim3(256), 0, stream, mx, buf, row0);
  }
  hipLaunchKernelGGL(k_finalize, dim3(1), dim3(64), 0, stream, out);
}

// Round 9
// 324.814 us; speedup vs baseline: 1.1853x; 1.1853x over previous
//
#include <hip/hip_runtime.h>
#include <math.h>

#define ROWS 64
#define TLEN 64000
#define NFR 251
#define NMELS 80
#define NFB 131072            // big FFT length (>= 2*T-1 -> exact linear conv)
#define PI2F 6.28318530717958647692f
#define PI_F 3.14159265358979323846f

// banked double accumulators:
// 0 S_dt  1 S_rt  2 S_sp  3..6 E0..E3  7 S_mag  8 S_cos  9 S_mel  10 S_c
__device__ double g_part[64][12];

// slot holding k2 after per-lane radix-4 FFT16 (digit reversal, involution)
__device__ constexpr int DR[16] = {0,4,8,12,1,5,9,13,2,6,10,14,3,7,11,15};
// mirror slot: RM[r] = DR[16 - DR[r]]
__device__ constexpr int RM[16] = {0,3,2,1,15,14,13,12,11,10,9,8,7,6,5,4};

__device__ inline int dr4(int i){ return ((i & 3) << 2) | (i >> 2); }  // DR, runtime
// bank-conflict-free swizzle for stride-16 writes into 513-entry arrays
__device__ inline int SW(int k){ return k + (k >> 5); }

__device__ inline void atomAddD(double* p, double v){
  __hip_atomic_fetch_add(p, v, __ATOMIC_RELAXED, __HIP_MEMORY_SCOPE_AGENT);
}
__device__ inline int brev6(int x){ return (int)((unsigned)__brev((unsigned)x) >> 26); }
__device__ inline float2 cmul(float2 a, float2 b){
  return make_float2(a.x*b.x - a.y*b.y, a.x*b.y + a.y*b.x);
}
__device__ inline float wred(float v){
#pragma unroll
  for (int o = 32; o > 0; o >>= 1) v += __shfl_down(v, o, 64);
  return v;
}

// ---------- per-wave FFT cores (forward DIF: natural in, bit-reversed out) ----------
template<int S, int N>
__device__ inline void fft64_lanes(float2* v, int l){
  float2 W[5];
#pragma unroll
  for (int si = 0; si < 5; ++si){
    int d = 32 >> si;
    float a = (float)S * PI_F * (float)(l & (d-1)) * (1.0f/(float)d);
    float sn, cs; __sincosf(a, &sn, &cs);
    W[si] = make_float2(cs, sn);
  }
#pragma unroll
  for (int rr = 0; rr < N; ++rr){
    float2 x = v[rr];
#pragma unroll
    for (int si = 0; si < 6; ++si){
      int d = 32 >> si;
      float tx = __shfl_xor(x.x, d, 64);
      float ty = __shfl_xor(x.y, d, 64);
      bool hi = (l & d) != 0;
      float sx = x.x + tx, sy = x.y + ty;
      float dx = tx - x.x, dy = ty - x.y;
      float rx, ry;
      if (si < 5){ rx = dx*W[si].x - dy*W[si].y; ry = dx*W[si].y + dy*W[si].x; }
      else       { rx = dx; ry = dy; }
      x.x = hi ? rx : sx;
      x.y = hi ? ry : sy;
    }
    v[rr] = x;
  }
}

template<int S>
__device__ inline void fft16_reg(float2* v){
  const float Sf = (float)S;
  const float C1 = 0.9238795325112867f, S1 = 0.3826834323650898f, C2 = 0.7071067811865476f;
  const float2 W1[4] = {{1.f,0.f},{C1,Sf*S1},{C2,Sf*C2},{S1,Sf*C1}};
  const float2 W2[4] = {{1.f,0.f},{C2,Sf*C2},{0.f,Sf},{-C2,Sf*C2}};
  const float2 W3[4] = {{1.f,0.f},{S1,Sf*C1},{-C2,Sf*C2},{-C1,-Sf*S1}};
#pragma unroll
  for (int j = 0; j < 4; ++j){
    float2 x0=v[j], x1=v[j+4], x2=v[j+8], x3=v[j+12];
    float2 t0={x0.x+x2.x, x0.y+x2.y}, t1={x0.x-x2.x, x0.y-x2.y};
    float2 t2={x1.x+x3.x, x1.y+x3.y}, t3={x1.x-x3.x, x1.y-x3.y};
    float2 y0={t0.x+t2.x, t0.y+t2.y};
    float2 y2={t0.x-t2.x, t0.y-t2.y};
    float2 y1={t1.x - Sf*t3.y, t1.y + Sf*t3.x};
    float2 y3={t1.x + Sf*t3.y, t1.y - Sf*t3.x};
    v[j]=y0; v[j+4]=cmul(y1,W1[j]); v[j+8]=cmul(y2,W2[j]); v[j+12]=cmul(y3,W3[j]);
  }
#pragma unroll
  for (int b = 0; b < 4; ++b){
    float2 x0=v[4*b], x1=v[4*b+1], x2=v[4*b+2], x3=v[4*b+3];
    float2 t0={x0.x+x2.x, x0.y+x2.y}, t1={x0.x-x2.x, x0.y-x2.y};
    float2 t2={x1.x+x3.x, x1.y+x3.y}, t3={x1.x-x3.x, x1.y-x3.y};
    v[4*b]   = make_float2(t0.x+t2.x, t0.y+t2.y);
    v[4*b+2] = make_float2(t0.x-t2.x, t0.y-t2.y);
    v[4*b+1] = make_float2(t1.x - Sf*t3.y, t1.y + Sf*t3.x);
    v[4*b+3] = make_float2(t1.x + Sf*t3.y, t1.y - Sf*t3.x);
  }
}

// 1024-pt forward: input v[m]=x[l+64m]; output slot rr, lane l = X[DR[rr]+16*brev6(l)]
template<int S>
__device__ inline void fft1024_wave(float2* v, int l){
  fft16_reg<S>(v);
  float a = (float)S * PI2F * (float)l * (1.0f/1024.0f);
  float sn, cs; __sincosf(a, &sn, &cs);
  float2 T = make_float2(cs, sn);
  float2 cur = T;
#pragma unroll
  for (int k2 = 1; k2 < 16; ++k2){
    v[DR[k2]] = cmul(v[DR[k2]], cur);
    if (k2 < 15) cur = cmul(cur, T);
  }
  fft64_lanes<S,16>(v, l);
}

// 128-pt forward: input v[m]=x[l+64m]; output slot rr, lane l = X[rr+2*brev6(l)]
template<int S>
__device__ inline void fft128_wave(float2* v, int l){
  float2 a = {v[0].x+v[1].x, v[0].y+v[1].y};
  float2 b = {v[0].x-v[1].x, v[0].y-v[1].y};
  float ang = (float)S * PI_F * (float)l * (1.0f/64.0f);
  float sn, cs; __sincosf(ang, &sn, &cs);
  v[0] = a; v[1] = cmul(b, make_float2(cs, sn));
  fft64_lanes<S,2>(v, l);
}

// ---------- adjoint (DIT) inverses: bit-reversed in, natural out, unnormalized ----------
template<int N>
__device__ inline void ifft64_lanes(float2* v, int l){
  float2 W[5];
#pragma unroll
  for (int si = 0; si < 5; ++si){
    int d = 32 >> si;
    float a = PI_F * (float)(l & (d-1)) * (1.0f/(float)d);   // conj of forward
    float sn, cs; __sincosf(a, &sn, &cs);
    W[si] = make_float2(cs, sn);
  }
#pragma unroll
  for (int rr = 0; rr < N; ++rr){
    float2 x = v[rr];
#pragma unroll
    for (int si = 5; si >= 0; --si){
      int d = 32 >> si;
      bool hi = (l & d) != 0;
      float2 xp = x;
      if (si < 5 && hi) xp = cmul(x, W[si]);
      float tx = __shfl_xor(xp.x, d, 64);
      float ty = __shfl_xor(xp.y, d, 64);
      x.x = hi ? (tx - xp.x) : (xp.x + tx);
      x.y = hi ? (ty - xp.y) : (xp.y + ty);
    }
    v[rr] = x;
  }
}

__device__ inline void r4p(float2* v, int i0, int i1, int i2, int i3){
  float2 x0=v[i0], x1=v[i1], x2=v[i2], x3=v[i3];
  float2 t0={x0.x+x2.x, x0.y+x2.y}, t1={x0.x-x2.x, x0.y-x2.y};
  float2 t2={x1.x+x3.x, x1.y+x3.y}, t3={x1.x-x3.x, x1.y-x3.y};
  v[i0] = make_float2(t0.x+t2.x, t0.y+t2.y);
  v[i2] = make_float2(t0.x-t2.x, t0.y-t2.y);
  v[i1] = make_float2(t1.x - t3.y, t1.y + t3.x);
  v[i3] = make_float2(t1.x + t3.y, t1.y - t3.x);
}

__device__ inline void ifft16_reg(float2* v){
#pragma unroll
  for (int b = 0; b < 4; ++b) r4p(v, 4*b, 4*b+1, 4*b+2, 4*b+3);
  const float C1 = 0.9238795325112867f, S1 = 0.3826834323650898f, C2 = 0.7071067811865476f;
  const float2 W1[4] = {{1.f,0.f},{C1,S1},{C2,C2},{S1,C1}};
  const float2 W2[4] = {{1.f,0.f},{C2,C2},{0.f,1.f},{-C2,C2}};
  const float2 W3[4] = {{1.f,0.f},{S1,C1},{-C2,C2},{-C1,-S1}};
#pragma unroll
  for (int j = 1; j < 4; ++j){
    v[j+4]  = cmul(v[j+4],  W1[j]);
    v[j+8]  = cmul(v[j+8],  W2[j]);
    v[j+12] = cmul(v[j+12], W3[j]);
  }
#pragma unroll
  for (int j = 0; j < 4; ++j) r4p(v, j, j+4, j+8, j+12);
}

// input slot rr, lane l = X[rr+2*brev6(l)]; output v[m], lane l = 128*x[l+64m]
__device__ inline void ifft128_wave(float2* v, int l){
  ifft64_lanes<2>(v, l);
  float ang = PI_F * (float)l * (1.0f/64.0f);
  float sn, cs; __sincosf(ang, &sn, &cs);
  v[1] = cmul(v[1], make_float2(cs, sn));
  float2 a = {v[0].x+v[1].x, v[0].y+v[1].y};
  float2 b = {v[0].x-v[1].x, v[0].y-v[1].y};
  v[0] = a; v[1] = b;
}

// input slot rr, lane l = X[DR[rr]+16*brev6(l)]; output v[m], lane l = 1024*x[l+64m]
__device__ inline void ifft1024_wave(float2* v, int l){
  ifft64_lanes<16>(v, l);
  float a = PI2F * (float)l * (1.0f/1024.0f);
  float sn, cs; __sincosf(a, &sn, &cs);
  float2 T = make_float2(cs, sn);
  float2 cur = T;
#pragma unroll
  for (int k2 = 1; k2 < 16; ++k2){
    v[DR[k2]] = cmul(v[DR[k2]], cur);
    if (k2 < 15) cur = cmul(cur, T);
  }
  ifft16_reg(v);
}

// ---------------- init: zero accumulators ----------------
extern "C" __global__ void __launch_bounds__(256) k_init(){
  int t = blockIdx.x*256 + threadIdx.x;
  if (t < 768) ((double*)g_part)[t] = 0.0;
}

// ---------------- time-domain losses + rir segment energies (float4) -------
extern "C" __global__ void __launch_bounds__(256) k_time(
    const float* __restrict__ pd, const float* __restrict__ td,
    const float* __restrict__ pr, const float* __restrict__ tr){
  const int N4 = ROWS*TLEN/4;          // 1,024,000 float4s; 16000 per row
  int stride = gridDim.x * 256;
  float sdt=0.f, srt=0.f, ssp=0.f, e0=0.f, e1=0.f, e2=0.f, e3=0.f;
  const float4* pd4 = (const float4*)pd;
  const float4* td4 = (const float4*)td;
  const float4* pr4 = (const float4*)pr;
  const float4* tr4 = (const float4*)tr;
  for (int i = blockIdx.x*256 + threadIdx.x; i < N4; i += stride){
    float4 a = pd4[i], b = td4[i], p = pr4[i], q = tr4[i];
    sdt += fabsf(a.x-b.x)+fabsf(a.y-b.y)+fabsf(a.z-b.z)+fabsf(a.w-b.w);
    srt += fabsf(p.x-q.x)+fabsf(p.y-q.y)+fabsf(p.z-q.z)+fabsf(p.w-q.w);
    ssp += fabsf(p.x)+fabsf(p.y)+fabsf(p.z)+fabsf(p.w);
    float p2 = p.x*p.x + p.y*p.y + p.z*p.z + p.w*p.w;
    int seg = (i % 16000) / 4000;      // uniform for all 4 elems
    if (seg == 0) e0 += p2; else if (seg == 1) e1 += p2;
    else if (seg == 2) e2 += p2; else e3 += p2;
  }
  sdt = wred(sdt); srt = wred(srt); ssp = wred(ssp);
  e0 = wred(e0); e1 = wred(e1); e2 = wred(e2); e3 = wred(e3);
  if ((threadIdx.x & 63) == 0){
    int bank = (blockIdx.x*4 + (threadIdx.x >> 6)) & 63;
    atomAddD(&g_part[bank][0], (double)sdt);
    atomAddD(&g_part[bank][1], (double)srt);
    atomAddD(&g_part[bank][2], (double)ssp);
    atomAddD(&g_part[bank][3], (double)e0);
    atomAddD(&g_part[bank][4], (double)e1);
    atomAddD(&g_part[bank][5], (double)e2);
    atomAddD(&g_part[bank][6], (double)e3);
  }
}

// ---------------- fused STFT (freq + mel) losses, one wave per frame --------
extern "C" __global__ void __launch_bounds__(256) k_stft(
    const float* __restrict__ pd, const float* __restrict__ td){
  __shared__ float2 spec0[4][64];
  __shared__ float pp[4][532], tt[4][532];   // swizzled index SW(k)=k+(k>>5)
  __shared__ float win[1024];
  int wid = threadIdx.x >> 6, l = threadIdx.x & 63;
  int tid = threadIdx.x;
  const float scale = 0.05103103630798288f;   // 1/sqrt(384), folded into window
  for (int j = tid; j < 1024; j += 256)
    win[j] = (0.5f - 0.5f*__cosf((PI2F/1024.0f)*(float)j)) * scale;
  __syncthreads();
  int frame = blockIdx.x*4 + wid;
  int r = frame / NFR, fr = frame - r*NFR;
  const float* pdr = pd + (size_t)r*TLEN;
  const float* tdr = td + (size_t)r*TLEN;
  int base = fr*256 - 512;
  float2 v[16];
#pragma unroll
  for (int m = 0; m < 16; ++m){
    int j = l + 64*m;
    int g = base + j;
    g = (g < 0) ? -g : ((g >= TLEN) ? (2*TLEN - 2 - g) : g);
    float w = win[j];
    v[m] = make_float2(pdr[g]*w, tdr[g]*w);
  }
  fft1024_wave<-1>(v, l);
  int kb = brev6(l);
  spec0[wid][kb] = v[0];          // the k2=0 line: Z[16*k1] at index k1
  float magp = 0.f, cosp = 0.f;
  // k2 = 1..15 lines: mirror of (slot rr, lane l) is (slot RM[rr], lane l^63).
  // Each unordered (k,1024-k) pair enumerated twice -> weight 0.5 (dup writes identical).
#pragma unroll
  for (int rr = 1; rr < 16; ++rr){
    float2 z = v[rr];
    float2 zm;
    zm.x = __shfl_xor(v[RM[rr]].x, 63, 64);
    zm.y = __shfl_xor(v[RM[rr]].y, 63, 64);
    int k = DR[rr] + 16*kb;
    float px = 0.5f*(z.x + zm.x), py = 0.5f*(z.y - zm.y);
    float tx = 0.5f*(z.y + zm.y), ty = -0.5f*(z.x - zm.x);
    float ppk = px*px + py*py, ttk = tx*tx + ty*ty;
    float rp = rsqrtf(fmaxf(ppk, 1e-30f)), rt = rsqrtf(fmaxf(ttk, 1e-30f));
    magp += 0.5f*fabsf(ppk*rp - ttk*rt);
    cosp += 0.5f*((px*tx + py*ty)*rp*rt);
    int kk = (k <= 512) ? k : 1024 - k;
    pp[wid][SW(kk)] = ppk; tt[wid][SW(kk)] = ttk;
  }
  if (l <= 32){                    // k = 16*l, weight 1
    float2 z  = spec0[wid][l];
    float2 zm = spec0[wid][(64 - l) & 63];
    float px = 0.5f*(z.x + zm.x), py = 0.5f*(z.y - zm.y);
    float tx = 0.5f*(z.y + zm.y), ty = -0.5f*(z.x - zm.x);
    float ppk = px*px + py*py, ttk = tx*tx + ty*ty;
    float rp = rsqrtf(fmaxf(ppk, 1e-30f)), rt = rsqrtf(fmaxf(ttk, 1e-30f));
    magp += fabsf(ppk*rp - ttk*rt);
    cosp += (px*tx + py*ty)*rp*rt;
    pp[wid][SW(16*l)] = ppk; tt[wid][SW(16*l)] = ttk;
  }
  // mel: same-wave LDS (program order guarantees pp/tt visibility within the wave)
  float melp = 0.f;
  // f(m) = 700*(exp(C*m)-1), C = maxmel/81/2595*ln10  (hardware exp)
  const float C = (2595.0f * log10f(1.0f + 8000.0f/700.0f))
                  * (1.0f/81.0f) * (1.0f/2595.0f) * 2.302585093f;
#pragma unroll
  for (int pass = 0; pass < 2; ++pass){
    int m = l + 64*pass;           // pairs narrow (l) with wide (l+64) filters
    if (m < NMELS){
      float f0 = 700.0f*(__expf(C*(float)(m  )) - 1.0f);
      float f1 = 700.0f*(__expf(C*(float)(m+1)) - 1.0f);
      float f2 = 700.0f*(__expf(C*(float)(m+2)) - 1.0f);
      float i1 = 1.0f/(f1 - f0), i2 = 1.0f/(f2 - f1);
      const float df = 15.625f;
      int lo = (int)ceilf(f0 * (1.0f/df));  if (lo < 0) lo = 0;
      int hi = (int)floorf(f2 * (1.0f/df)); if (hi > 512) hi = 512;
      float pm = 0.f, tm = 0.f;
      for (int k = lo; k <= hi; ++k){
        float frq = df*(float)k;
        float c = fminf((frq - f0)*i1, (f2 - frq)*i2);
        c = fmaxf(c, 0.f);
        int sk = SW(k);
        pm += c*pp[wid][sk]; tm += c*tt[wid][sk];
      }
      melp += fabsf(__logf(pm + 1e-8f) - __logf(tm + 1e-8f));
    }
  }
  magp = wred(magp); cosp = wred(cosp); melp = wred(melp);
  if (l == 0){
    int bank = (blockIdx.x*4 + wid) & 63;
    atomAddD(&g_part[bank][7], (double)magp);
    atomAddD(&g_part[bank][8], (double)cosp);
    atomAddD(&g_part[bank][9], (double)melp);
  }
}

// ---------------- consistency: four-step FFT of 131072 = 128 x 1024 ---------
// n = n1 + 128*n2 ; storage: buf[s*128 + n1], s = rr*64 + l
// fwd1: block = 8 waves = 8 adjacent n1. LDS-staged coalesced global I/O.
// LDS phases aliased in one 41 KB pool: input [500][10]x2 (40 KB) then
// transpose chunks [8][513] float2 (32.8 KB) -> ~3 blocks/CU.
extern "C" __global__ void __launch_bounds__(512) k_fwd1(
    const float* __restrict__ pd, const float* __restrict__ pr,
    float2* __restrict__ buf, int row0){
  __shared__ float SM[10256];                    // 41 KB
  float* LA = SM;                                // [500][10] floats (a)
  float* LB = SM + 5000;                         // [500][10] floats (b)
  float2* LT = (float2*)SM;                      // [8][513] float2 (chunks)
  int wid = threadIdx.x >> 6, l = threadIdx.x & 63;
  int tid = threadIdx.x;
  int rl = blockIdx.y;
  int n1base = blockIdx.x * 8;
  int n1 = n1base + wid;
  const float* a = pd + (size_t)(row0+rl)*TLEN;
  const float* b = pr + (size_t)(row0+rl)*TLEN;
  for (int i = tid; i < 2000; i += 512){
    int n2 = i >> 2, wp = (i & 3)*2;
    float2 va = *(const float2*)&a[n1base + wp + 128*n2];
    float2 vb = *(const float2*)&b[n1base + wp + 128*n2];
    *(float2*)&LA[n2*10 + wp] = va;
    *(float2*)&LB[n2*10 + wp] = vb;
  }
  __syncthreads();
  float2 v[16];
#pragma unroll
  for (int m = 0; m < 16; ++m){
    int n2 = l + 64*m;
    if (n2 < 500) v[m] = make_float2(LA[n2*10 + wid], LB[n2*10 + wid]);
    else          v[m] = make_float2(0.f, 0.f);
  }
  __syncthreads();                                // LA/LB reads done (LT aliases)
  fft1024_wave<-1>(v, l);
  int kb = brev6(l);
  const float tw = -(PI2F / (float)NFB);
#pragma unroll
  for (int rr = 0; rr < 16; ++rr){
    int K = DR[rr] + 16*kb;
    float ang = tw * (float)(n1*K);               // n1*K < 2^24: exact
    float sn, cs; __sincosf(ang, &sn, &cs);
    v[rr] = cmul(v[rr], make_float2(cs, sn));
  }
  float2* rowp = buf + (size_t)rl*NFB;
#pragma unroll
  for (int c = 0; c < 2; ++c){
#pragma unroll
    for (int rrl = 0; rrl < 8; ++rrl)
      LT[wid*513 + rrl*64 + l] = v[c*8 + rrl];
    __syncthreads();
#pragma unroll
    for (int it = 0; it < 4; ++it){
      int g = (tid + it*512)*2;                   // complex index in chunk, even
      int s = g >> 3, nw = g & 7;                 // s in [0,512), nw in {0,2,4,6}
      float2 x = LT[nw*513 + s], y = LT[(nw+1)*513 + s];
      *(float4*)&rowp[(size_t)(c*512 + s)*128 + n1base + nw] =
          make_float4(x.x, x.y, y.x, y.y);
    }
    __syncthreads();
  }
}

// D/R split + product for one element (z) given its mirror partner (zm)
__device__ inline float2 pointmul(float2 z, float2 zm){
  float Dx = 0.5f*(z.x + zm.x), Dy = 0.5f*(z.y - zm.y);
  float Rx = 0.5f*(z.y + zm.y), Ry = -0.5f*(z.x - zm.x);
  return make_float2(Dx*Rx - Dy*Ry, Dx*Ry + Dy*Rx);
}

// k_mid: fused fwd2 + pointwise + inv1. One wave per conjugate row pair.
extern "C" __global__ void __launch_bounds__(256) k_mid(float2* __restrict__ buf){
  int wid = threadIdx.x >> 6, l = threadIdx.x & 63;
  int p = blockIdx.x*4 + wid;           // pair id = k2 of row A, 0..512
  if (p > 512) return;
  int k2A = p, k2B = (1024 - p) & 1023;
  int sA = dr4(k2A & 15)*64 + brev6(k2A >> 4);
  int sB = dr4(k2B & 15)*64 + brev6(k2B >> 4);
  float2* base = buf + (size_t)blockIdx.y*NFB;
  float2* rA = base + (size_t)sA*128;
  float2* rB = base + (size_t)sB*128;
  bool pair = (sB != sA);
  float2 vA[2] = { rA[l], rA[l+64] };
  float2 vB[2];
  if (pair){ vB[0] = rB[l]; vB[1] = rB[l+64]; }
  fft128_wave<-1>(vA, l);
  if (pair) fft128_wave<-1>(vB, l);
  float2 cA[2];
  if (p == 0){
    int kb = brev6(l);
    int q0 = brev6((64 - kb) & 63);
    float2 zm0 = { __shfl(vA[0].x, q0, 64), __shfl(vA[0].y, q0, 64) };
    float2 zm1 = { __shfl_xor(vA[1].x, 63, 64), __shfl_xor(vA[1].y, 63, 64) };
    cA[0] = pointmul(vA[0], zm0);
    cA[1] = pointmul(vA[1], zm1);
  } else {
    const float2* src = pair ? vB : vA;   // p==512 self-pairs within its own row
    float2 zm0 = { __shfl_xor(src[1].x, 63, 64), __shfl_xor(src[1].y, 63, 64) };
    float2 zm1 = { __shfl_xor(src[0].x, 63, 64), __shfl_xor(src[0].y, 63, 64) };
    cA[0] = pointmul(vA[0], zm0);
    cA[1] = pointmul(vA[1], zm1);
  }
  float2 cB[2];
  if (pair){
    cB[0] = make_float2( __shfl_xor(cA[1].x, 63, 64), -__shfl_xor(cA[1].y, 63, 64) );
    cB[1] = make_float2( __shfl_xor(cA[0].x, 63, 64), -__shfl_xor(cA[0].y, 63, 64) );
  }
  const float twi = PI2F / (float)NFB;
  ifft128_wave(cA, l);
#pragma unroll
  for (int rr = 0; rr < 2; ++rr){
    int n1 = l + 64*rr;
    float ang = twi * (float)(n1*k2A);
    float sn, cs; __sincosf(ang, &sn, &cs);
    rA[n1] = cmul(cA[rr], make_float2(cs, sn));
  }
  if (pair){
    ifft128_wave(cB, l);
#pragma unroll
    for (int rr = 0; rr < 2; ++rr){
      int n1 = l + 64*rr;
      float ang = twi * (float)(n1*k2B);
      float sn, cs; __sincosf(ang, &sn, &cs);
      rB[n1] = cmul(cB[rr], make_float2(cs, sn));
    }
  }
}

// inv2: per n1, adjoint inverse 1024-pt FFT (storage order in, natural out);
// chunked LDS-staged coalesced loads + fused |rec - mix| reduction
extern "C" __global__ void __launch_bounds__(512) k_inv2(
    const float* __restrict__ mix, float2* __restrict__ buf, int row0){
  __shared__ float SM[10256];                    // 41 KB, aliased phases
  float2* LT = (float2*)SM;                      // [8][513] float2 (chunks)
  float* LM = SM;                                // [500][10] floats (mix)
  int wid = threadIdx.x >> 6, l = threadIdx.x & 63;
  int tid = threadIdx.x;
  int rl = blockIdx.y;
  int n1base = blockIdx.x * 8;
  float2* rowp = buf + (size_t)rl*NFB;
  float2 v[16];
#pragma unroll
  for (int c = 0; c < 2; ++c){
#pragma unroll
    for (int it = 0; it < 4; ++it){
      int g = (tid + it*512)*2;
      int s = g >> 3, nw = g & 7;
      float4 q = *(const float4*)&rowp[(size_t)(c*512 + s)*128 + n1base + nw];
      LT[nw*513 + s]     = make_float2(q.x, q.y);
      LT[(nw+1)*513 + s] = make_float2(q.z, q.w);
    }
    __syncthreads();
#pragma unroll
    for (int rrl = 0; rrl < 8; ++rrl)
      v[c*8 + rrl] = LT[wid*513 + rrl*64 + l];
    __syncthreads();                              // LT reads done before reuse
  }
  const float* mr = mix + (size_t)(row0+rl)*TLEN;
  for (int i = tid; i < 2000; i += 512){
    int n2 = i >> 2, wp = (i & 3)*2;
    *(float2*)&LM[n2*10 + wp] = *(const float2*)&mr[n1base + wp + 128*n2];
  }
  ifft1024_wave(v, l);
  __syncthreads();                                // LM ready
  const float invn = 1.0f/(float)NFB;
  float acc = 0.f;
#pragma unroll
  for (int m = 0; m < 16; ++m){
    int n2 = l + 64*m;
    if (n2 < 500)
      acc += fabsf(v[m].x*invn - LM[n2*10 + wid]);
  }
  acc = wred(acc);
  if (l == 0){
    int bank = (blockIdx.x*8 + wid + blockIdx.y*16) & 63;
    atomAddD(&g_part[bank][10], (double)acc);
  }
}

// ---------------- combine ----------------
extern "C" __global__ void __launch_bounds__(64) k_finalize(float* __restrict__ out){
  __shared__ double s[12];
  int t = threadIdx.x;
  if (t < 12){
    double v = 0.0;
    for (int b = 0; b < 64; ++b) v += g_part[b][t];
    s[t] = v;
  }
  __syncthreads();
  if (t == 0){
    double dt = s[0] / 4096000.0;
    double rt = s[1] / 4096000.0;
    double sp = s[2] / 4096000.0;
    double e0 = s[3] / 1024000.0, e1 = s[4] / 1024000.0;
    double e2 = s[5] / 1024000.0, e3 = s[6] / 1024000.0;
    double dec = fmax(e1 - 0.8*e0, 0.0) + fmax(e2 - 0.8*e1, 0.0) + fmax(e3 - 0.8*e2, 0.0);
    double c1 = 8240832.0;              // 64*513*251
    double freq = s[7]/c1 + 0.1*(1.0 - s[8]/c1);
    double mel  = s[9] / 1285120.0;     // 64*80*251
    double cons = s[10] / 4096000.0;
    double total = 3.0*(dt + 0.5*freq + 0.3*mel)
                 + (rt + 0.1*(sp + dec))
                 + 0.2*cons;
    out[0] = (float)total;
  }
}

extern "C" void kernel_launch(void* const* d_in, const int* in_sizes, int n_in,
                              void* d_out, int out_size, void* d_ws, size_t ws_size,
                              hipStream_t stream){
  const float* pd = (const float*)d_in[0];
  const float* pr = (const float*)d_in[1];
  const float* td = (const float*)d_in[2];
  const float* tr = (const float*)d_in[3];
  const float* mx = (const float*)d_in[4];
  float* out = (float*)d_out;
  float2* buf = (float2*)d_ws;

  size_t rowBytes = (size_t)NFB * sizeof(float2);     // 1 MiB per row
  int maxrows = (int)(ws_size / rowBytes);
  if (maxrows > ROWS) maxrows = ROWS;
  if (maxrows < 1) maxrows = 1;
  // balanced chunking: avoid runt chunks like 31/31/2
  int nch = (ROWS + maxrows - 1) / maxrows;
  int chrows = (ROWS + nch - 1) / nch;

  hipLaunchKernelGGL(k_init, dim3(3), dim3(256), 0, stream);
  hipLaunchKernelGGL(k_time, dim3(2048), dim3(256), 0, stream, pd, td, pr, tr);
  hipLaunchKernelGGL(k_stft, dim3(ROWS*NFR/4), dim3(256), 0, stream, pd, td);
  for (int row0 = 0; row0 < ROWS; row0 += chrows){
    int nr = ROWS - row0; if (nr > chrows) nr = chrows;
    hipLaunchKernelGGL(k_fwd1, dim3(16, nr),  dim3(512), 0, stream, pd, pr, buf, row0);
    hipLaunchKernelGGL(k_mid,  dim3(129, nr), dim3(256), 0, stream, buf);
    hipLaunchKernelGGL(k_inv2, dim3(16, nr),  dim3(512), 0, stream, mx, buf, row0);
  }
  hipLaunchKernelGGL(k_finalize, dim3(1), dim3(64), 0, stream, out);
}